// Round 2
// baseline (231.042 us; speedup 1.0000x reference)
//
#include <hip/hip_runtime.h>
#include <cstdint>
#include <cstddef>

#define NN 8192
#define NE 131072
#define EMB 256

typedef float f32x4 __attribute__((ext_vector_type(4)));
typedef __bf16 bf16x8 __attribute__((ext_vector_type(8)));

__device__ __forceinline__ unsigned short f2bf(float f) {
  unsigned u = __float_as_uint(f);
  u += 0x7fffu + ((u >> 16) & 1u);   // round-to-nearest-even
  return (unsigned short)(u >> 16);
}

__device__ __forceinline__ void gload_lds16(const void* g, void* l) {
  __builtin_amdgcn_global_load_lds(
      (const __attribute__((address_space(1))) unsigned int*)g,
      (__attribute__((address_space(3))) unsigned int*)l, 16, 0, 0);
}

// ---------- fused: node head + bf16 convert + sq norms (single read of node_emb) ----------
// block = 256 threads = 16 rows; thread (r = tid>>4, g = tid&15)
__global__ __launch_bounds__(256) void node_prep_kernel(const float* __restrict__ X,
                                                        const float* __restrict__ w,
                                                        const float* __restrict__ bias,
                                                        float* __restrict__ out,
                                                        unsigned short* __restrict__ Xb,
                                                        float* __restrict__ sq) {
  __shared__ float xs[16 * 260];   // stride 260 words: 16B-aligned rows, group-spread banks
  int tid = threadIdx.x;
  int n0  = blockIdx.x * 16;
  int r   = tid >> 4, g = tid & 15;

  float s = 0.f;
  #pragma unroll
  for (int kc = 0; kc < 4; ++kc) {
    float4 v = *(const float4*)(X + (size_t)(n0 + r) * EMB + kc * 64 + g * 4);
    *(float4*)(&xs[r * 260 + kc * 64 + g * 4]) = v;
    s += v.x * v.x + v.y * v.y + v.z * v.z + v.w * v.w;
    ushort4 b;
    b.x = f2bf(v.x); b.y = f2bf(v.y); b.z = f2bf(v.z); b.w = f2bf(v.w);
    *(ushort4*)(Xb + (size_t)(n0 + r) * EMB + kc * 64 + g * 4) = b;
  }
  // reduce sq across the 16 threads of this row (lanes g within a 16-lane group)
  s += __shfl_xor(s, 1); s += __shfl_xor(s, 2);
  s += __shfl_xor(s, 4); s += __shfl_xor(s, 8);
  if (g == 0) sq[n0 + r] = s;
  __syncthreads();

  // head: thread computes row e=r, outputs o0..o0+3
  int o0 = g * 4;
  float acc[4] = {0.f, 0.f, 0.f, 0.f};
  #pragma unroll 4
  for (int k = 0; k < 256; k += 4) {
    float4 x = *(const float4*)(&xs[r * 260 + k]);   // broadcast within group
    #pragma unroll
    for (int oo = 0; oo < 4; ++oo) {
      float4 wv = *(const float4*)(w + (size_t)(o0 + oo) * EMB + k);
      acc[oo] = fmaf(x.x, wv.x, fmaf(x.y, wv.y, fmaf(x.z, wv.z, fmaf(x.w, wv.w, acc[oo]))));
    }
  }
  float4 o;
  o.x = acc[0] + bias[o0 + 0];
  o.y = acc[1] + bias[o0 + 1];
  o.z = acc[2] + bias[o0 + 2];
  o.w = acc[3] + bias[o0 + 3];
  *(float4*)(out + (size_t)(n0 + r) * 64 + o0) = o;
}

// ---------- edge head: [131072x256] @ [256x16]^T + bias, f32 ----------
// 256 edges/block, 16-col rounds (17.4 KB LDS -> 8 blocks/CU), T14 issue-early/write-late
__global__ __launch_bounds__(256) void edge_head_kernel(const float* __restrict__ X,
                                                        const float* __restrict__ w,
                                                        const float* __restrict__ bias,
                                                        float* __restrict__ out) {
  __shared__ float xs[256 * 17];
  int tid = threadIdx.x;
  int e0  = blockIdx.x * 256;
  int lr  = tid >> 2, lc = (tid & 3) * 4;   // load slot: 4 rows (lr + q*64), 4 cols

  float4 v[4];
  #pragma unroll
  for (int q = 0; q < 4; ++q)
    v[q] = *(const float4*)(X + (size_t)(e0 + lr + q * 64) * EMB + lc);

  float acc[16];
  #pragma unroll
  for (int o = 0; o < 16; ++o) acc[o] = 0.f;

  for (int kc = 0; kc < 16; ++kc) {
    __syncthreads();
    #pragma unroll
    for (int q = 0; q < 4; ++q) {
      float* d = &xs[(lr + q * 64) * 17 + lc];
      d[0] = v[q].x; d[1] = v[q].y; d[2] = v[q].z; d[3] = v[q].w;
    }
    __syncthreads();
    if (kc < 15) {
      #pragma unroll
      for (int q = 0; q < 4; ++q)
        v[q] = *(const float4*)(X + (size_t)(e0 + lr + q * 64) * EMB + (kc + 1) * 16 + lc);
    }
    const float* wk0 = w + kc * 16;   // uniform -> s_load
    #pragma unroll
    for (int k = 0; k < 16; ++k) {
      float x = xs[tid * 17 + k];
      #pragma unroll
      for (int o = 0; o < 16; ++o)
        acc[o] = fmaf(x, wk0[(size_t)o * EMB + k], acc[o]);
    }
  }
  #pragma unroll
  for (int o = 0; o < 16; ++o) acc[o] += bias[o];
  float4* dst = (float4*)(out + (size_t)(e0 + tid) * 16);
  dst[0] = make_float4(acc[0], acc[1], acc[2], acc[3]);
  dst[1] = make_float4(acc[4], acc[5], acc[6], acc[7]);
  dst[2] = make_float4(acc[8], acc[9], acc[10], acc[11]);
  dst[3] = make_float4(acc[12], acc[13], acc[14], acc[15]);
}

// ---------- adj: sigmoid(W*(|xi|^2+|xj|^2-2 xi.xj)+b), zero diag, SYMMETRIC ----------
// Lower-triangle 128x128 tiles only (2080 blocks); mirror tile stored via LDS transpose.
__global__ __launch_bounds__(256) void adj_kernel(const unsigned short* __restrict__ Xb,
                                                  const float* __restrict__ sq,
                                                  const float* __restrict__ Wp,
                                                  const float* __restrict__ bp,
                                                  float* __restrict__ out) {
  __shared__ __align__(16) char smem[32768];
  unsigned short* As = (unsigned short*)smem;        // [128][64] bf16
  unsigned short* Bs = As + 128 * 64;                // [128][64] bf16
  float* TR = (float*)smem;                          // [64][128] f32 (epilogue reuse)

  int b   = blockIdx.x;
  int swz = (b & 7) * 260 + (b >> 3);                // XCD swizzle, 2080 = 8*260
  int ti  = (int)((sqrtf(8.0f * (float)swz + 1.0f) - 1.0f) * 0.5f);
  while ((ti + 1) * (ti + 2) / 2 <= swz) ++ti;
  while (ti * (ti + 1) / 2 > swz) --ti;
  int tj = swz - ti * (ti + 1) / 2;                  // 0 <= tj <= ti

  int tid  = threadIdx.x;
  int wave = tid >> 6, lane = tid & 63;
  int wr = (wave >> 1) * 64;   // wave row origin in tile
  int wc = (wave & 1) * 64;    // wave col origin in tile
  int l15 = lane & 15, lg = lane >> 4;

  f32x4 acc[4][4] = {};

  int r_base = tid >> 3;         // + it*32
  int cb     = (tid & 7) << 4;   // byte col within 128B LDS row

  for (int kt = 0; kt < 4; ++kt) {
    #pragma unroll
    for (int it = 0; it < 4; ++it) {
      int r   = it * 32 + r_base;
      int cbs = cb ^ ((r & 7) << 4);            // inverse-swizzled source col
      int col = (kt << 6) + (cbs >> 1);
      const unsigned short* ga = Xb + (size_t)(ti * 128 + r) * EMB + col;
      const unsigned short* gb = Xb + (size_t)(tj * 128 + r) * EMB + col;
      gload_lds16(ga, (char*)As + it * 4096 + wave * 1024);
      gload_lds16(gb, (char*)Bs + it * 4096 + wave * 1024);
    }
    __syncthreads();
    #pragma unroll
    for (int ks = 0; ks < 2; ++ks) {
      bf16x8 af[4], bfr[4];
      #pragma unroll
      for (int m = 0; m < 4; ++m) {
        int rr = wr + m * 16 + l15;
        int bc = ((ks << 6) + (lg << 4)) ^ ((rr & 7) << 4);
        af[m] = *(const bf16x8*)((const char*)As + rr * 128 + bc);
      }
      #pragma unroll
      for (int n = 0; n < 4; ++n) {
        int rr = wc + n * 16 + l15;
        int bc = ((ks << 6) + (lg << 4)) ^ ((rr & 7) << 4);
        bfr[n] = *(const bf16x8*)((const char*)Bs + rr * 128 + bc);
      }
      #pragma unroll
      for (int m = 0; m < 4; ++m)
        #pragma unroll
        for (int n = 0; n < 4; ++n)
          acc[m][n] = __builtin_amdgcn_mfma_f32_16x16x32_bf16(af[m], bfr[n], acc[m][n], 0, 0, 0);
    }
    __syncthreads();
  }

  // sigmoid in place (+ diag mask), then direct store of tile (ti,tj)
  float W0 = Wp[0], b0 = bp[0];
  float w2 = -2.0f * W0;
  int col0 = tj * 128 + wc + l15;
  int row0 = ti * 128 + wr + (lg << 2);

  float aiW[16];
  #pragma unroll
  for (int m = 0; m < 4; ++m)
    #pragma unroll
    for (int rg = 0; rg < 4; ++rg)
      aiW[m * 4 + rg] = W0 * sq[row0 + m * 16 + rg];

  #pragma unroll
  for (int n = 0; n < 4; ++n) {
    int j = col0 + n * 16;
    float sjW = fmaf(W0, sq[j], b0);
    #pragma unroll
    for (int m = 0; m < 4; ++m) {
      #pragma unroll
      for (int rg = 0; rg < 4; ++rg) {
        int i = row0 + m * 16 + rg;
        float t = fmaf(w2, acc[m][n][rg], aiW[m * 4 + rg] + sjW);
        float p = __builtin_amdgcn_rcpf(1.0f + __expf(-t));
        if (i == j) p = 0.0f;
        acc[m][n][rg] = p;
        out[(size_t)i * NN + j] = p;
      }
    }
  }

  // mirror store of tile (tj,ti) via LDS transpose (skip diagonal blocks)
  if (ti != tj) {
    int my_half = wc >> 6;   // 0 for waves 0,2 ; 1 for waves 1,3
    #pragma unroll
    for (int h = 0; h < 2; ++h) {
      if (my_half == h) {
        #pragma unroll
        for (int n = 0; n < 4; ++n) {
          int jr = n * 16 + l15;                    // local mirror row within half
          #pragma unroll
          for (int m = 0; m < 4; ++m) {
            int i0   = wr + m * 16 + (lg << 2);
            int word = jr * 128 + ((i0 + 4 * jr) & 127);   // rotate-4 swizzle
            *(f32x4*)(&TR[word]) = acc[m][n];
          }
        }
      }
      __syncthreads();
      #pragma unroll
      for (int q = 0; q < 8; ++q) {
        int jr   = q * 8 + wave * 2 + (lane >> 5);
        int i0   = (lane & 31) * 4;
        int word = jr * 128 + ((i0 + 4 * jr) & 127);
        f32x4 val = *(const f32x4*)(&TR[word]);
        int rowg = tj * 128 + h * 64 + jr;
        int colg = ti * 128 + i0;
        *(f32x4*)(&out[(size_t)rowg * NN + colg]) = val;
      }
      __syncthreads();
    }
  }
}

extern "C" void kernel_launch(void* const* d_in, const int* in_sizes, int n_in,
                              void* d_out, int out_size, void* d_ws, size_t ws_size,
                              hipStream_t stream) {
  const float* node_emb = (const float*)d_in[0];
  const float* edge_emb = (const float*)d_in[1];
  const float* node_w   = (const float*)d_in[2];
  const float* node_b   = (const float*)d_in[3];
  const float* edge_w   = (const float*)d_in[4];
  const float* edge_b   = (const float*)d_in[5];
  const float* Wp       = (const float*)d_in[6];
  const float* bp       = (const float*)d_in[7];

  float* out      = (float*)d_out;
  float* node_out = out;                        // [8192 x 64]
  float* edge_out = out + (size_t)NN * 64;      // [131072 x 16]
  float* adj_out  = out + (size_t)NN * 64 + (size_t)NE * 16;  // [8192 x 8192]

  unsigned short* Xb = (unsigned short*)d_ws;                       // 4 MiB
  float* sq = (float*)((char*)d_ws + (size_t)NN * EMB * 2);         // 32 KiB

  node_prep_kernel<<<dim3(NN / 16), dim3(256), 0, stream>>>(node_emb, node_w, node_b,
                                                            node_out, Xb, sq);
  edge_head_kernel<<<dim3(NE / 256), dim3(256), 0, stream>>>(edge_emb, edge_w, edge_b, edge_out);
  adj_kernel<<<dim3(2080), dim3(256), 0, stream>>>(Xb, sq, Wp, bp, adj_out);
}

// Round 3
// 210.518 us; speedup vs baseline: 1.0975x; 1.0975x over previous
//
#include <hip/hip_runtime.h>
#include <cstdint>
#include <cstddef>

#define NN 8192
#define NE 131072
#define EMB 256

typedef float f32x4 __attribute__((ext_vector_type(4)));
typedef __bf16 bf16x8 __attribute__((ext_vector_type(8)));

__device__ __forceinline__ unsigned short f2bf(float f) {
  unsigned u = __float_as_uint(f);
  u += 0x7fffu + ((u >> 16) & 1u);   // round-to-nearest-even
  return (unsigned short)(u >> 16);
}

__device__ __forceinline__ void gload_lds16(const void* g, void* l) {
  __builtin_amdgcn_global_load_lds(
      (const __attribute__((address_space(1))) unsigned int*)g,
      (__attribute__((address_space(3))) unsigned int*)l, 16, 0, 0);
}

// ---------- fused heads: blocks 0..511 edge head, 512..1023 node head+prep ----------
__global__ __launch_bounds__(256) void heads_kernel(const float* __restrict__ Xn,
                                                    const float* __restrict__ nw,
                                                    const float* __restrict__ nb,
                                                    const float* __restrict__ Xe,
                                                    const float* __restrict__ ew,
                                                    const float* __restrict__ eb,
                                                    float* __restrict__ node_out,
                                                    float* __restrict__ edge_out,
                                                    unsigned short* __restrict__ Xb,
                                                    float* __restrict__ sq) {
  __shared__ float lds[256 * 17];   // 17.4 KB, shared by both paths
  int tid = threadIdx.x;

  if (blockIdx.x < 512) {
    // ===== edge head: 256 edges/block, [256x256]@[256x16]^T =====
    int e0 = blockIdx.x * 256;
    int lr = tid >> 2, lc = (tid & 3) * 4;   // 4 rows (lr + q*64), 4 cols

    float4 v[4];
    #pragma unroll
    for (int q = 0; q < 4; ++q)
      v[q] = *(const float4*)(Xe + (size_t)(e0 + lr + q * 64) * EMB + lc);

    float acc[16];
    #pragma unroll
    for (int o = 0; o < 16; ++o) acc[o] = 0.f;

    for (int kc = 0; kc < 16; ++kc) {
      __syncthreads();
      #pragma unroll
      for (int q = 0; q < 4; ++q) {
        float* d = &lds[(lr + q * 64) * 17 + lc];
        d[0] = v[q].x; d[1] = v[q].y; d[2] = v[q].z; d[3] = v[q].w;
      }
      __syncthreads();
      if (kc < 15) {
        #pragma unroll
        for (int q = 0; q < 4; ++q)
          v[q] = *(const float4*)(Xe + (size_t)(e0 + lr + q * 64) * EMB + (kc + 1) * 16 + lc);
      }
      const float* wk0 = ew + kc * 16;   // uniform -> s_load
      #pragma unroll
      for (int k = 0; k < 16; ++k) {
        float x = lds[tid * 17 + k];
        #pragma unroll
        for (int o = 0; o < 16; ++o)
          acc[o] = fmaf(x, wk0[(size_t)o * EMB + k], acc[o]);
      }
    }
    #pragma unroll
    for (int o = 0; o < 16; ++o) acc[o] += eb[o];
    float4* dst = (float4*)(edge_out + (size_t)(e0 + tid) * 16);
    dst[0] = make_float4(acc[0], acc[1], acc[2], acc[3]);
    dst[1] = make_float4(acc[4], acc[5], acc[6], acc[7]);
    dst[2] = make_float4(acc[8], acc[9], acc[10], acc[11]);
    dst[3] = make_float4(acc[12], acc[13], acc[14], acc[15]);
  } else {
    // ===== node head + bf16 convert + sq norms: 16 rows/block =====
    int n0 = (blockIdx.x - 512) * 16;
    int r = tid >> 4, g = tid & 15;
    float* xs = lds;   // use rows of stride 260 within 256*17 floats? 16*260=4160 < 4352 ok

    float s = 0.f;
    #pragma unroll
    for (int kc = 0; kc < 4; ++kc) {
      float4 v = *(const float4*)(Xn + (size_t)(n0 + r) * EMB + kc * 64 + g * 4);
      *(float4*)(&xs[r * 260 + kc * 64 + g * 4]) = v;
      s += v.x * v.x + v.y * v.y + v.z * v.z + v.w * v.w;
      ushort4 b;
      b.x = f2bf(v.x); b.y = f2bf(v.y); b.z = f2bf(v.z); b.w = f2bf(v.w);
      *(ushort4*)(Xb + (size_t)(n0 + r) * EMB + kc * 64 + g * 4) = b;
    }
    s += __shfl_xor(s, 1); s += __shfl_xor(s, 2);
    s += __shfl_xor(s, 4); s += __shfl_xor(s, 8);
    if (g == 0) sq[n0 + r] = s;
    __syncthreads();

    int o0 = g * 4;
    float acc[4] = {0.f, 0.f, 0.f, 0.f};
    #pragma unroll 4
    for (int k = 0; k < 256; k += 4) {
      float4 x = *(const float4*)(&xs[r * 260 + k]);
      #pragma unroll
      for (int oo = 0; oo < 4; ++oo) {
        float4 wv = *(const float4*)(nw + (size_t)(o0 + oo) * EMB + k);
        acc[oo] = fmaf(x.x, wv.x, fmaf(x.y, wv.y, fmaf(x.z, wv.z, fmaf(x.w, wv.w, acc[oo]))));
      }
    }
    float4 o;
    o.x = acc[0] + nb[o0 + 0];
    o.y = acc[1] + nb[o0 + 1];
    o.z = acc[2] + nb[o0 + 2];
    o.w = acc[3] + nb[o0 + 3];
    *(float4*)(node_out + (size_t)(n0 + r) * 64 + o0) = o;
  }
}

// ---------- adj: sigmoid(W*(|xi|^2+|xj|^2-2 xi.xj)+b), zero diag, SYMMETRIC ----------
// Lower-triangle 128x128 tiles (2080 blocks). Output symmetry: value for (i,j) can be
// stored at (j,i). Mirror square (tj-rows, ti-cols) stored as coalesced float4 direct
// from registers; direct square (ti-rows, tj-cols) via 64B-segment scalar stores,
// skipped entirely for diagonal tiles (same square).
__global__ __launch_bounds__(256) void adj_kernel(const unsigned short* __restrict__ Xb,
                                                  const float* __restrict__ sq,
                                                  const float* __restrict__ Wp,
                                                  const float* __restrict__ bp,
                                                  float* __restrict__ out) {
  __shared__ __align__(16) unsigned short As[128 * 64];
  __shared__ __align__(16) unsigned short Bs[128 * 64];

  int b   = blockIdx.x;
  int swz = (b & 7) * 260 + (b >> 3);                // XCD swizzle, 2080 = 8*260
  int ti  = (int)((sqrtf(8.0f * (float)swz + 1.0f) - 1.0f) * 0.5f);
  while ((ti + 1) * (ti + 2) / 2 <= swz) ++ti;
  while (ti * (ti + 1) / 2 > swz) --ti;
  int tj = swz - ti * (ti + 1) / 2;                  // 0 <= tj <= ti

  int tid  = threadIdx.x;
  int wave = tid >> 6, lane = tid & 63;
  int wr = (wave >> 1) * 64;   // wave row origin in tile
  int wc = (wave & 1) * 64;    // wave col origin in tile
  int l15 = lane & 15, lg = lane >> 4;

  f32x4 acc[4][4] = {};

  int r_base = tid >> 3;         // + it*32
  int cb     = (tid & 7) << 4;   // byte col within 128B LDS row

  for (int kt = 0; kt < 4; ++kt) {
    #pragma unroll
    for (int it = 0; it < 4; ++it) {
      int r   = it * 32 + r_base;
      int cbs = cb ^ ((r & 7) << 4);            // inverse-swizzled source col
      int col = (kt << 6) + (cbs >> 1);
      const unsigned short* ga = Xb + (size_t)(ti * 128 + r) * EMB + col;
      const unsigned short* gb = Xb + (size_t)(tj * 128 + r) * EMB + col;
      gload_lds16(ga, (char*)As + it * 4096 + wave * 1024);
      gload_lds16(gb, (char*)Bs + it * 4096 + wave * 1024);
    }
    __syncthreads();
    #pragma unroll
    for (int ks = 0; ks < 2; ++ks) {
      bf16x8 af[4], bfr[4];
      #pragma unroll
      for (int m = 0; m < 4; ++m) {
        int rr = wr + m * 16 + l15;
        int bc = ((ks << 6) + (lg << 4)) ^ ((rr & 7) << 4);
        af[m] = *(const bf16x8*)((const char*)As + rr * 128 + bc);
      }
      #pragma unroll
      for (int n = 0; n < 4; ++n) {
        int rr = wc + n * 16 + l15;
        int bc = ((ks << 6) + (lg << 4)) ^ ((rr & 7) << 4);
        bfr[n] = *(const bf16x8*)((const char*)Bs + rr * 128 + bc);
      }
      #pragma unroll
      for (int m = 0; m < 4; ++m)
        #pragma unroll
        for (int n = 0; n < 4; ++n)
          acc[m][n] = __builtin_amdgcn_mfma_f32_16x16x32_bf16(af[m], bfr[n], acc[m][n], 0, 0, 0);
    }
    __syncthreads();
  }

  float W0 = Wp[0], b0 = bp[0];
  float w2 = -2.0f * W0;
  int col0 = tj * 128 + wc + l15;           // j for this lane
  int row0 = ti * 128 + wr + (lg << 2);     // first of 4 consecutive i (per m: +m*16)

  float aiW[16];
  #pragma unroll
  for (int m = 0; m < 4; ++m)
    #pragma unroll
    for (int rg = 0; rg < 4; ++rg)
      aiW[m * 4 + rg] = W0 * sq[row0 + m * 16 + rg];

  bool offdiag = (ti != tj);
  #pragma unroll
  for (int n = 0; n < 4; ++n) {
    int j = col0 + n * 16;
    float sjW = fmaf(W0, sq[j], b0);
    #pragma unroll
    for (int m = 0; m < 4; ++m) {
      #pragma unroll
      for (int rg = 0; rg < 4; ++rg) {
        int i = row0 + m * 16 + rg;
        float t = fmaf(w2, acc[m][n][rg], aiW[m * 4 + rg] + sjW);
        float p = __builtin_amdgcn_rcpf(1.0f + __expf(-t));
        if (i == j) p = 0.0f;
        acc[m][n][rg] = p;
        if (offdiag) out[(size_t)i * NN + j] = p;   // direct square, 64B segments
      }
      // mirror square from registers: (j, i0..i0+3) coalesced float4
      *(f32x4*)(&out[(size_t)j * NN + row0 + m * 16]) = acc[m][n];
    }
  }
}

extern "C" void kernel_launch(void* const* d_in, const int* in_sizes, int n_in,
                              void* d_out, int out_size, void* d_ws, size_t ws_size,
                              hipStream_t stream) {
  const float* node_emb = (const float*)d_in[0];
  const float* edge_emb = (const float*)d_in[1];
  const float* node_w   = (const float*)d_in[2];
  const float* node_b   = (const float*)d_in[3];
  const float* edge_w   = (const float*)d_in[4];
  const float* edge_b   = (const float*)d_in[5];
  const float* Wp       = (const float*)d_in[6];
  const float* bp       = (const float*)d_in[7];

  float* out      = (float*)d_out;
  float* node_out = out;                        // [8192 x 64]
  float* edge_out = out + (size_t)NN * 64;      // [131072 x 16]
  float* adj_out  = out + (size_t)NN * 64 + (size_t)NE * 16;  // [8192 x 8192]

  unsigned short* Xb = (unsigned short*)d_ws;                       // 4 MiB
  float* sq = (float*)((char*)d_ws + (size_t)NN * EMB * 2);         // 32 KiB

  heads_kernel<<<dim3(1024), dim3(256), 0, stream>>>(node_emb, node_w, node_b,
                                                     edge_emb, edge_w, edge_b,
                                                     node_out, edge_out, Xb, sq);
  adj_kernel<<<dim3(2080), dim3(256), 0, stream>>>(Xb, sq, Wp, bp, adj_out);
}

// Round 4
// 192.549 us; speedup vs baseline: 1.1999x; 1.0933x over previous
//
#include <hip/hip_runtime.h>
#include <cstdint>
#include <cstddef>

#define NN 8192
#define NE 131072
#define EMB 256

typedef float f32x4 __attribute__((ext_vector_type(4)));
typedef __bf16 bf16x8 __attribute__((ext_vector_type(8)));

__device__ __forceinline__ unsigned short f2bf(float f) {
  unsigned u = __float_as_uint(f);
  u += 0x7fffu + ((u >> 16) & 1u);   // round-to-nearest-even
  return (unsigned short)(u >> 16);
}

__device__ __forceinline__ void gload_lds16(const void* g, void* l) {
  __builtin_amdgcn_global_load_lds(
      (const __attribute__((address_space(1))) unsigned int*)g,
      (__attribute__((address_space(3))) unsigned int*)l, 16, 0, 0);
}

// ---------- fused heads: blocks 0..511 edge head, 512..1023 node head+prep ----------
__global__ __launch_bounds__(256) void heads_kernel(const float* __restrict__ Xn,
                                                    const float* __restrict__ nw,
                                                    const float* __restrict__ nb,
                                                    const float* __restrict__ Xe,
                                                    const float* __restrict__ ew,
                                                    const float* __restrict__ eb,
                                                    float* __restrict__ node_out,
                                                    float* __restrict__ edge_out,
                                                    unsigned short* __restrict__ Xb,
                                                    float* __restrict__ sq) {
  __shared__ float lds[256 * 17];   // 17.4 KB, shared by both paths
  int tid = threadIdx.x;

  if (blockIdx.x < 512) {
    // ===== edge head: 256 edges/block, [256x256]@[256x16]^T =====
    int e0 = blockIdx.x * 256;
    int lr = tid >> 2, lc = (tid & 3) * 4;   // 4 rows (lr + q*64), 4 cols

    float4 v[4];
    #pragma unroll
    for (int q = 0; q < 4; ++q)
      v[q] = *(const float4*)(Xe + (size_t)(e0 + lr + q * 64) * EMB + lc);

    float acc[16];
    #pragma unroll
    for (int o = 0; o < 16; ++o) acc[o] = 0.f;

    for (int kc = 0; kc < 16; ++kc) {
      __syncthreads();
      #pragma unroll
      for (int q = 0; q < 4; ++q) {
        float* d = &lds[(lr + q * 64) * 17 + lc];
        d[0] = v[q].x; d[1] = v[q].y; d[2] = v[q].z; d[3] = v[q].w;
      }
      __syncthreads();
      if (kc < 15) {
        #pragma unroll
        for (int q = 0; q < 4; ++q)
          v[q] = *(const float4*)(Xe + (size_t)(e0 + lr + q * 64) * EMB + (kc + 1) * 16 + lc);
      }
      const float* wk0 = ew + kc * 16;   // uniform -> s_load
      #pragma unroll
      for (int k = 0; k < 16; ++k) {
        float x = lds[tid * 17 + k];
        #pragma unroll
        for (int o = 0; o < 16; ++o)
          acc[o] = fmaf(x, wk0[(size_t)o * EMB + k], acc[o]);
      }
    }
    #pragma unroll
    for (int o = 0; o < 16; ++o) acc[o] += eb[o];
    float4* dst = (float4*)(edge_out + (size_t)(e0 + tid) * 16);
    dst[0] = make_float4(acc[0], acc[1], acc[2], acc[3]);
    dst[1] = make_float4(acc[4], acc[5], acc[6], acc[7]);
    dst[2] = make_float4(acc[8], acc[9], acc[10], acc[11]);
    dst[3] = make_float4(acc[12], acc[13], acc[14], acc[15]);
  } else {
    // ===== node head + bf16 convert + sq norms: 16 rows/block =====
    int n0 = (blockIdx.x - 512) * 16;
    int r = tid >> 4, g = tid & 15;
    float* xs = lds;   // rows of stride 260 fit: 16*260 = 4160 < 4352

    float s = 0.f;
    #pragma unroll
    for (int kc = 0; kc < 4; ++kc) {
      float4 v = *(const float4*)(Xn + (size_t)(n0 + r) * EMB + kc * 64 + g * 4);
      *(float4*)(&xs[r * 260 + kc * 64 + g * 4]) = v;
      s += v.x * v.x + v.y * v.y + v.z * v.z + v.w * v.w;
      ushort4 b;
      b.x = f2bf(v.x); b.y = f2bf(v.y); b.z = f2bf(v.z); b.w = f2bf(v.w);
      *(ushort4*)(Xb + (size_t)(n0 + r) * EMB + kc * 64 + g * 4) = b;
    }
    s += __shfl_xor(s, 1); s += __shfl_xor(s, 2);
    s += __shfl_xor(s, 4); s += __shfl_xor(s, 8);
    if (g == 0) sq[n0 + r] = s;
    __syncthreads();

    int o0 = g * 4;
    float acc[4] = {0.f, 0.f, 0.f, 0.f};
    #pragma unroll 4
    for (int k = 0; k < 256; k += 4) {
      float4 x = *(const float4*)(&xs[r * 260 + k]);
      #pragma unroll
      for (int oo = 0; oo < 4; ++oo) {
        float4 wv = *(const float4*)(nw + (size_t)(o0 + oo) * EMB + k);
        acc[oo] = fmaf(x.x, wv.x, fmaf(x.y, wv.y, fmaf(x.z, wv.z, fmaf(x.w, wv.w, acc[oo]))));
      }
    }
    float4 o;
    o.x = acc[0] + nb[o0 + 0];
    o.y = acc[1] + nb[o0 + 1];
    o.z = acc[2] + nb[o0 + 2];
    o.w = acc[3] + nb[o0 + 3];
    *(float4*)(node_out + (size_t)(n0 + r) * 64 + o0) = o;
  }
}

// ---------- adj: sigmoid(W*(|xi|^2+|xj|^2-2 xi.xj)+b), zero diag, SYMMETRIC ----------
// FULL 64x64 tile grid. Block (ti,tj) computes tile values v[i in I][j in J] and, using
// adj(i,j)=adj(j,i), stores ONLY the transposed square: out[j][i] — which is float4-
// coalescible straight from the MFMA fragment (lane holds 4 consecutive i for fixed j).
// Every output element is written exactly once (by the block with swapped tile coords).
// All stores nontemporal: 268 MB streams shouldn't evict L2-resident Xb.
__global__ __launch_bounds__(256) void adj_kernel(const unsigned short* __restrict__ Xb,
                                                  const float* __restrict__ sq,
                                                  const float* __restrict__ Wp,
                                                  const float* __restrict__ bp,
                                                  float* __restrict__ out) {
  __shared__ __align__(16) unsigned short As[128 * 64];
  __shared__ __align__(16) unsigned short Bs[128 * 64];

  int b   = blockIdx.x;
  int swz = (b & 7) * 512 + (b >> 3);   // XCD swizzle, 4096 % 8 == 0
  int ti  = swz >> 6, tj = swz & 63;

  int tid  = threadIdx.x;
  int wave = tid >> 6, lane = tid & 63;
  int wr = (wave >> 1) * 64;   // wave row origin in tile
  int wc = (wave & 1) * 64;    // wave col origin in tile
  int l15 = lane & 15, lg = lane >> 4;

  f32x4 acc[4][4] = {};

  int r_base = tid >> 3;         // + it*32
  int cb     = (tid & 7) << 4;   // byte col within 128B LDS row

  for (int kt = 0; kt < 4; ++kt) {
    #pragma unroll
    for (int it = 0; it < 4; ++it) {
      int r   = it * 32 + r_base;
      int cbs = cb ^ ((r & 7) << 4);            // inverse-swizzled source col
      int col = (kt << 6) + (cbs >> 1);
      const unsigned short* ga = Xb + (size_t)(ti * 128 + r) * EMB + col;
      const unsigned short* gb = Xb + (size_t)(tj * 128 + r) * EMB + col;
      gload_lds16(ga, (char*)As + it * 4096 + wave * 1024);
      gload_lds16(gb, (char*)Bs + it * 4096 + wave * 1024);
    }
    __syncthreads();
    #pragma unroll
    for (int ks = 0; ks < 2; ++ks) {
      bf16x8 af[4], bfr[4];
      #pragma unroll
      for (int m = 0; m < 4; ++m) {
        int rr = wr + m * 16 + l15;
        int bc = ((ks << 6) + (lg << 4)) ^ ((rr & 7) << 4);
        af[m] = *(const bf16x8*)((const char*)As + rr * 128 + bc);
      }
      #pragma unroll
      for (int n = 0; n < 4; ++n) {
        int rr = wc + n * 16 + l15;
        int bc = ((ks << 6) + (lg << 4)) ^ ((rr & 7) << 4);
        bfr[n] = *(const bf16x8*)((const char*)Bs + rr * 128 + bc);
      }
      #pragma unroll
      for (int m = 0; m < 4; ++m)
        #pragma unroll
        for (int n = 0; n < 4; ++n)
          acc[m][n] = __builtin_amdgcn_mfma_f32_16x16x32_bf16(af[m], bfr[n], acc[m][n], 0, 0, 0);
    }
    __syncthreads();
  }

  float W0 = Wp[0], b0 = bp[0];
  float w2 = -2.0f * W0;
  int col0 = tj * 128 + wc + l15;           // j for this lane
  int row0 = ti * 128 + wr + (lg << 2);     // first of 4 consecutive i (per m: +m*16)
  bool diag = (ti == tj);

  float aiW[16];
  #pragma unroll
  for (int m = 0; m < 4; ++m)
    #pragma unroll
    for (int rg = 0; rg < 4; ++rg)
      aiW[m * 4 + rg] = W0 * sq[row0 + m * 16 + rg];

  #pragma unroll
  for (int n = 0; n < 4; ++n) {
    int j = col0 + n * 16;
    float sjW = fmaf(W0, sq[j], b0);
    #pragma unroll
    for (int m = 0; m < 4; ++m) {
      #pragma unroll
      for (int rg = 0; rg < 4; ++rg) {
        float t = fmaf(w2, acc[m][n][rg], aiW[m * 4 + rg] + sjW);
        acc[m][n][rg] = __builtin_amdgcn_rcpf(1.0f + __expf(-t));
      }
      if (diag) {
        #pragma unroll
        for (int rg = 0; rg < 4; ++rg)
          if (row0 + m * 16 + rg == j) acc[m][n][rg] = 0.0f;
      }
      // transposed-square store: row j, cols i0..i0+3 — coalesced float4, streaming
      __builtin_nontemporal_store(acc[m][n],
          (f32x4*)(&out[(size_t)j * NN + row0 + m * 16]));
    }
  }
}

extern "C" void kernel_launch(void* const* d_in, const int* in_sizes, int n_in,
                              void* d_out, int out_size, void* d_ws, size_t ws_size,
                              hipStream_t stream) {
  const float* node_emb = (const float*)d_in[0];
  const float* edge_emb = (const float*)d_in[1];
  const float* node_w   = (const float*)d_in[2];
  const float* node_b   = (const float*)d_in[3];
  const float* edge_w   = (const float*)d_in[4];
  const float* edge_b   = (const float*)d_in[5];
  const float* Wp       = (const float*)d_in[6];
  const float* bp       = (const float*)d_in[7];

  float* out      = (float*)d_out;
  float* node_out = out;                        // [8192 x 64]
  float* edge_out = out + (size_t)NN * 64;      // [131072 x 16]
  float* adj_out  = out + (size_t)NN * 64 + (size_t)NE * 16;  // [8192 x 8192]

  unsigned short* Xb = (unsigned short*)d_ws;                       // 4 MiB
  float* sq = (float*)((char*)d_ws + (size_t)NN * EMB * 2);         // 32 KiB

  heads_kernel<<<dim3(1024), dim3(256), 0, stream>>>(node_emb, node_w, node_b,
                                                     edge_emb, edge_w, edge_b,
                                                     node_out, edge_out, Xb, sq);
  adj_kernel<<<dim3(4096), dim3(256), 0, stream>>>(Xb, sq, Wp, bp, adj_out);
}

// Round 5
// 180.592 us; speedup vs baseline: 1.2794x; 1.0662x over previous
//
#include <hip/hip_runtime.h>
#include <cstdint>
#include <cstddef>

#define NN 8192
#define NE 131072
#define EMB 256

typedef float f32x4 __attribute__((ext_vector_type(4)));
typedef __bf16 bf16x8 __attribute__((ext_vector_type(8)));

__device__ __forceinline__ unsigned short f2bf(float f) {
  unsigned u = __float_as_uint(f);
  u += 0x7fffu + ((u >> 16) & 1u);   // round-to-nearest-even
  return (unsigned short)(u >> 16);
}

__device__ __forceinline__ void gload_lds16(const void* g, void* l) {
  __builtin_amdgcn_global_load_lds(
      (const __attribute__((address_space(1))) unsigned int*)g,
      (__attribute__((address_space(3))) unsigned int*)l, 16, 0, 0);
}

// ---------- node head + bf16 convert + sq norms (must precede adj) ----------
__global__ __launch_bounds__(256) void node_prep_kernel(const float* __restrict__ X,
                                                        const float* __restrict__ w,
                                                        const float* __restrict__ bias,
                                                        float* __restrict__ out,
                                                        unsigned short* __restrict__ Xb,
                                                        float* __restrict__ sq) {
  __shared__ float xs[16 * 260];
  int tid = threadIdx.x;
  int n0  = blockIdx.x * 16;
  int r   = tid >> 4, g = tid & 15;

  float s = 0.f;
  #pragma unroll
  for (int kc = 0; kc < 4; ++kc) {
    float4 v = *(const float4*)(X + (size_t)(n0 + r) * EMB + kc * 64 + g * 4);
    *(float4*)(&xs[r * 260 + kc * 64 + g * 4]) = v;
    s += v.x * v.x + v.y * v.y + v.z * v.z + v.w * v.w;
    ushort4 b;
    b.x = f2bf(v.x); b.y = f2bf(v.y); b.z = f2bf(v.z); b.w = f2bf(v.w);
    *(ushort4*)(Xb + (size_t)(n0 + r) * EMB + kc * 64 + g * 4) = b;
  }
  s += __shfl_xor(s, 1); s += __shfl_xor(s, 2);
  s += __shfl_xor(s, 4); s += __shfl_xor(s, 8);
  if (g == 0) sq[n0 + r] = s;
  __syncthreads();

  int o0 = g * 4;
  float acc[4] = {0.f, 0.f, 0.f, 0.f};
  #pragma unroll 4
  for (int k = 0; k < 256; k += 4) {
    float4 x = *(const float4*)(&xs[r * 260 + k]);
    #pragma unroll
    for (int oo = 0; oo < 4; ++oo) {
      float4 wv = *(const float4*)(w + (size_t)(o0 + oo) * EMB + k);
      acc[oo] = fmaf(x.x, wv.x, fmaf(x.y, wv.y, fmaf(x.z, wv.z, fmaf(x.w, wv.w, acc[oo]))));
    }
  }
  float4 o;
  o.x = acc[0] + bias[o0 + 0];
  o.y = acc[1] + bias[o0 + 1];
  o.z = acc[2] + bias[o0 + 2];
  o.w = acc[3] + bias[o0 + 3];
  *(float4*)(out + (size_t)(n0 + r) * 64 + o0) = o;
}

// ---------- mega: adj (8 of every 9 blocks) + edge head (every 9th block) ----------
// adj tile map (assuming HW XCD = blockIdx%8): per XCD, ti is one of 8 fixed rows
// (A-panels resident forever, 256 KB); each B-panel is used by ~8 temporally-adjacent
// blocks then never again. Per-XCD instantaneous working set ~768 KB << 4 MiB L2.
// Edge blocks interleave 1:8, smoothing their 134 MB HBM read across the timeline.
__global__ __launch_bounds__(256) void mega_kernel(const unsigned short* __restrict__ Xb,
                                                   const float* __restrict__ sq,
                                                   const float* __restrict__ Wp,
                                                   const float* __restrict__ bp,
                                                   float* __restrict__ adj_out,
                                                   const float* __restrict__ Xe,
                                                   const float* __restrict__ ew,
                                                   const float* __restrict__ eb,
                                                   float* __restrict__ edge_out) {
  __shared__ __align__(16) char smem[32768];
  int tid = threadIdx.x;
  int b   = blockIdx.x;           // 0..4607
  int g   = b / 9, rem = b - g * 9;

  if (rem == 8) {
    // ===== edge head: 256 edges/block =====
    float* lds = (float*)smem;    // 256*17 floats = 17.4 KB
    int e0 = g * 256;
    int lr = tid >> 2, lc = (tid & 3) * 4;

    float4 v[4];
    #pragma unroll
    for (int q = 0; q < 4; ++q)
      v[q] = *(const float4*)(Xe + (size_t)(e0 + lr + q * 64) * EMB + lc);

    float acc[16];
    #pragma unroll
    for (int o = 0; o < 16; ++o) acc[o] = 0.f;

    for (int kc = 0; kc < 16; ++kc) {
      __syncthreads();
      #pragma unroll
      for (int q = 0; q < 4; ++q) {
        float* d = &lds[(lr + q * 64) * 17 + lc];
        d[0] = v[q].x; d[1] = v[q].y; d[2] = v[q].z; d[3] = v[q].w;
      }
      __syncthreads();
      if (kc < 15) {
        #pragma unroll
        for (int q = 0; q < 4; ++q)
          v[q] = *(const float4*)(Xe + (size_t)(e0 + lr + q * 64) * EMB + (kc + 1) * 16 + lc);
      }
      const float* wk0 = ew + kc * 16;   // uniform -> s_load
      #pragma unroll
      for (int k = 0; k < 16; ++k) {
        float x = lds[tid * 17 + k];
        #pragma unroll
        for (int o = 0; o < 16; ++o)
          acc[o] = fmaf(x, wk0[(size_t)o * EMB + k], acc[o]);
      }
    }
    #pragma unroll
    for (int o = 0; o < 16; ++o) acc[o] += eb[o];
    float4* dst = (float4*)(edge_out + (size_t)(e0 + tid) * 16);
    dst[0] = make_float4(acc[0], acc[1], acc[2], acc[3]);
    dst[1] = make_float4(acc[4], acc[5], acc[6], acc[7]);
    dst[2] = make_float4(acc[8], acc[9], acc[10], acc[11]);
    dst[3] = make_float4(acc[12], acc[13], acc[14], acc[15]);
    return;
  }

  // ===== adj tile =====
  unsigned short* As = (unsigned short*)smem;        // [128][64] bf16
  unsigned short* Bs = As + 128 * 64;                // [128][64] bf16

  int adjid = g * 8 + rem;                // 0..4095, per-XCD ~sequential in q=adjid>>3
  int low3  = adjid & 7, q = adjid >> 3;  // q tracks time order within an XCD
  int ti = low3 * 8 + (q & 7);            // 8 fixed A-rows per XCD
  int tj = ((q >> 6) & 7) * 8 + ((q >> 3) & 7);   // B-panel live ~8 blocks then done

  int wave = tid >> 6, lane = tid & 63;
  int wr = (wave >> 1) * 64;
  int wc = (wave & 1) * 64;
  int l15 = lane & 15, lg = lane >> 4;

  f32x4 acc[4][4] = {};

  int r_base = tid >> 3;
  int cb     = (tid & 7) << 4;

  for (int kt = 0; kt < 4; ++kt) {
    #pragma unroll
    for (int it = 0; it < 4; ++it) {
      int r   = it * 32 + r_base;
      int cbs = cb ^ ((r & 7) << 4);
      int col = (kt << 6) + (cbs >> 1);
      const unsigned short* ga = Xb + (size_t)(ti * 128 + r) * EMB + col;
      const unsigned short* gb = Xb + (size_t)(tj * 128 + r) * EMB + col;
      gload_lds16(ga, (char*)As + it * 4096 + wave * 1024);
      gload_lds16(gb, (char*)Bs + it * 4096 + wave * 1024);
    }
    __syncthreads();
    #pragma unroll
    for (int ks = 0; ks < 2; ++ks) {
      bf16x8 af[4], bfr[4];
      #pragma unroll
      for (int m = 0; m < 4; ++m) {
        int rr = wr + m * 16 + l15;
        int bc = ((ks << 6) + (lg << 4)) ^ ((rr & 7) << 4);
        af[m] = *(const bf16x8*)((const char*)As + rr * 128 + bc);
      }
      #pragma unroll
      for (int n = 0; n < 4; ++n) {
        int rr = wc + n * 16 + l15;
        int bc = ((ks << 6) + (lg << 4)) ^ ((rr & 7) << 4);
        bfr[n] = *(const bf16x8*)((const char*)Bs + rr * 128 + bc);
      }
      #pragma unroll
      for (int m = 0; m < 4; ++m)
        #pragma unroll
        for (int n = 0; n < 4; ++n)
          acc[m][n] = __builtin_amdgcn_mfma_f32_16x16x32_bf16(af[m], bfr[n], acc[m][n], 0, 0, 0);
    }
    __syncthreads();
  }

  float W0 = Wp[0], b0 = bp[0];
  float w2 = -2.0f * W0;
  int col0 = tj * 128 + wc + l15;           // j for this lane
  int row0 = ti * 128 + wr + (lg << 2);     // first of 4 consecutive i (per m: +m*16)
  bool diag = (ti == tj);

  float aiW[16];
  #pragma unroll
  for (int m = 0; m < 4; ++m)
    #pragma unroll
    for (int rg = 0; rg < 4; ++rg)
      aiW[m * 4 + rg] = W0 * sq[row0 + m * 16 + rg];

  #pragma unroll
  for (int n = 0; n < 4; ++n) {
    int j = col0 + n * 16;
    float sjW = fmaf(W0, sq[j], b0);
    #pragma unroll
    for (int m = 0; m < 4; ++m) {
      #pragma unroll
      for (int rg = 0; rg < 4; ++rg) {
        float t = fmaf(w2, acc[m][n][rg], aiW[m * 4 + rg] + sjW);
        acc[m][n][rg] = __builtin_amdgcn_rcpf(1.0f + __expf(-t));
      }
      if (diag) {
        #pragma unroll
        for (int rg = 0; rg < 4; ++rg)
          if (row0 + m * 16 + rg == j) acc[m][n][rg] = 0.0f;
      }
      // adj(i,j)=adj(j,i): store transposed square only — coalesced float4, streaming
      __builtin_nontemporal_store(acc[m][n],
          (f32x4*)(&adj_out[(size_t)j * NN + row0 + m * 16]));
    }
  }
}

extern "C" void kernel_launch(void* const* d_in, const int* in_sizes, int n_in,
                              void* d_out, int out_size, void* d_ws, size_t ws_size,
                              hipStream_t stream) {
  const float* node_emb = (const float*)d_in[0];
  const float* edge_emb = (const float*)d_in[1];
  const float* node_w   = (const float*)d_in[2];
  const float* node_b   = (const float*)d_in[3];
  const float* edge_w   = (const float*)d_in[4];
  const float* edge_b   = (const float*)d_in[5];
  const float* Wp       = (const float*)d_in[6];
  const float* bp       = (const float*)d_in[7];

  float* out      = (float*)d_out;
  float* node_out = out;                        // [8192 x 64]
  float* edge_out = out + (size_t)NN * 64;      // [131072 x 16]
  float* adj_out  = out + (size_t)NN * 64 + (size_t)NE * 16;  // [8192 x 8192]

  unsigned short* Xb = (unsigned short*)d_ws;                       // 4 MiB
  float* sq = (float*)((char*)d_ws + (size_t)NN * EMB * 2);         // 32 KiB

  node_prep_kernel<<<dim3(512), dim3(256), 0, stream>>>(node_emb, node_w, node_b,
                                                        node_out, Xb, sq);
  mega_kernel<<<dim3(4608), dim3(256), 0, stream>>>(Xb, sq, Wp, bp, adj_out,
                                                    edge_emb, edge_w, edge_b, edge_out);
}